// Round 14
// baseline (176.577 us; speedup 1.0000x reference)
//
#include <hip/hip_runtime.h>
#include <cstdint>
#include <cstddef>

// VmfVectorQuantizer round 14: R9 structure (2 waves/16-row tile, 256 codes
// per wave, 4096x128, launch_bounds(128,2)) + ALL-4-tile upfront gumbel
// prefetch (u HBM latency leaves the pass-2 critical path) + 1024 scalar
// slots (8x less atomic line contention than 128).

typedef __attribute__((ext_vector_type(8))) short short8;
typedef __attribute__((ext_vector_type(4))) float f32x4;

namespace {
constexpr float kEpsG = 1e-10f;
constexpr float kEpsN = 1e-12f;
constexpr float kEpsP = 1e-7f;
constexpr float kLog2e = 1.4426950408889634f;
constexpr float kLn2 = 0.6931471805599453f;
constexpr int kSlots = 1024;
constexpr int kStride = 520;
}

__device__ __forceinline__ float wsum64(float v) {
#pragma unroll
    for (int m = 1; m < 64; m <<= 1) v += __shfl_xor(v, m, 64);
    return v;
}
__device__ __forceinline__ uint32_t pk_bf16(float a, float b) {
    uint32_t ua = __float_as_uint(a), ub = __float_as_uint(b);
    ua += 0x7fffu + ((ua >> 16) & 1u);
    ub += 0x7fffu + ((ub >> 16) & 1u);
    return (ua >> 16) | (ub & 0xffff0000u);
}
__device__ __forceinline__ uint16_t bf16_rne(float a) {
    uint32_t ua = __float_as_uint(a);
    ua += 0x7fffu + ((ua >> 16) & 1u);
    return (uint16_t)(ua >> 16);
}
__device__ __forceinline__ float dot4(float4 v) {
    return v.x * v.x + v.y * v.y + v.z * v.z + v.w * v.w;
}

__global__ __launch_bounds__(256) void k_prep(const float* __restrict__ cb,
                                              uint16_t* __restrict__ cbN,
                                              uint16_t* __restrict__ cbNT) {
    const int row = blockIdx.x * 4 + (threadIdx.x >> 6);
    const int lane = threadIdx.x & 63;
    const float v = cb[row * 64 + lane];
    const float ss = wsum64(v * v);
    const float nv = v / fmaxf(sqrtf(ss), kEpsN);
    const uint16_t h = bf16_rne(nv);
    cbN[row * 64 + lane] = h;
    cbNT[lane * 512 + row] = h;
}

// ---- k_main: 2 waves per 16-row tile; wave W owns codes [256W, 256W+256).
__global__ __launch_bounds__(128, 2) void k_main(
    const float* __restrict__ z, const float* __restrict__ kqp,
    const float* __restrict__ gum, const uint16_t* __restrict__ cbN,
    const uint16_t* __restrict__ cbNT, float* __restrict__ out,
    float* __restrict__ g_part) {
    __shared__ float avg_lds[512];
    __shared__ float cS[2][16], cW[2][16], cS2[2][16];
    __shared__ float4 accx[2][2][64];

    const int tid = threadIdx.x;
    const int W = tid >> 6;
    const int l = tid & 63;
    const int g = l >> 4;
    const int rh = l & 15;
    const int r0 = blockIdx.x * 16;
    const int row = r0 + rh;
    const float kq = *kqp;

    // ---- z load + L2 normalize; fold kq*log2e into bf16 B-fragments
    const float* zr = z + (size_t)row * 64;
    const float4 a0 = *(const float4*)(zr + 8 * g);
    const float4 a1 = *(const float4*)(zr + 8 * g + 4);
    const float4 a2 = *(const float4*)(zr + 32 + 8 * g);
    const float4 a3 = *(const float4*)(zr + 36 + 8 * g);
    float ss = dot4(a0) + dot4(a1) + dot4(a2) + dot4(a3);
    ss += __shfl_xor(ss, 16, 64);
    ss += __shfl_xor(ss, 32, 64);
    const float scz = kq * kLog2e / fmaxf(sqrtf(ss), kEpsN);
    union U8 { short8 s; uint32_t u[4]; };
    U8 zb0, zb1;
    zb0.u[0] = pk_bf16(a0.x * scz, a0.y * scz);
    zb0.u[1] = pk_bf16(a0.z * scz, a0.w * scz);
    zb0.u[2] = pk_bf16(a1.x * scz, a1.y * scz);
    zb0.u[3] = pk_bf16(a1.z * scz, a1.w * scz);
    zb1.u[0] = pk_bf16(a2.x * scz, a2.y * scz);
    zb1.u[1] = pk_bf16(a2.z * scz, a2.w * scz);
    zb1.u[2] = pk_bf16(a3.x * scz, a3.y * scz);
    zb1.u[3] = pk_bf16(a3.z * scz, a3.w * scz);

    const float B1 = kq * kLog2e;  // static bound: x <= B1

    // ---- ALL 4 u tiles prefetched upfront: 8 KB/wave in flight; vmcnt
    // in-order retirement completes them under pass 1's 32 MFMAs.
    const float* ur = gum + (size_t)row * 512 + 256 * W;
    float4 uN[4][4];
#pragma unroll
    for (int t = 0; t < 4; ++t)
#pragma unroll
        for (int j = 0; j < 4; ++j)
            uN[t][j] = *(const float4*)(ur + 64 * t + 16 * j + 4 * g);

    const uint16_t* cbW = cbN + (size_t)(256 * W) * 64;

    // ================= pass 1: logits -> e (bf16-packed), S, W ============
    uint32_t epk[32];
    float S4[4] = {0.f, 0.f, 0.f, 0.f}, W4[4] = {0.f, 0.f, 0.f, 0.f};
#pragma unroll
    for (int T = 0; T < 4; ++T) {
        short8 ca[8];
#pragma unroll
        for (int q = 0; q < 4; ++q) {
            const uint16_t* cr = cbW + (size_t)((64 * T + 16 * q + rh) * 64);
            ca[2 * q] = *(const short8*)(cr + 8 * g);
            ca[2 * q + 1] = *(const short8*)(cr + 32 + 8 * g);
        }
#pragma unroll
        for (int q = 0; q < 4; ++q) {
            f32x4 acc = {0.f, 0.f, 0.f, 0.f};
            acc = __builtin_amdgcn_mfma_f32_16x16x32_bf16(ca[2 * q], zb0.s, acc, 0, 0, 0);
            acc = __builtin_amdgcn_mfma_f32_16x16x32_bf16(ca[2 * q + 1], zb1.s, acc, 0, 0, 0);
            float e4[4];
#pragma unroll
            for (int i = 0; i < 4; ++i) {
                const float d = acc[i] - B1;
                const float e = __builtin_amdgcn_exp2f(d);
                e4[i] = e;
                S4[i] += e;
                W4[i] = fmaf(d, e, W4[i]);
            }
            epk[8 * T + 2 * q] = pk_bf16(e4[0], e4[1]);
            epk[8 * T + 2 * q + 1] = pk_bf16(e4[2], e4[3]);
        }
    }
    float Sr = (S4[0] + S4[1]) + (S4[2] + S4[3]);
    float Wr = (W4[0] + W4[1]) + (W4[2] + W4[3]);
    Sr += __shfl_xor(Sr, 16, 64);
    Sr += __shfl_xor(Sr, 32, 64);
    Wr += __shfl_xor(Wr, 16, 64);
    Wr += __shfl_xor(Wr, 32, 64);
    if (g == 0) { cS[W][rh] = Sr; cW[W][rh] = Wr; }
    __syncthreads();
    const float St = cS[0][rh] + cS[1][rh];
    const float Wt = cW[0][rh] + cW[1][rh];
    const float inv = 1.0f / St;
    const float kldd = kLn2 * (Wt * inv - __builtin_amdgcn_logf(St));

    // ================= pass 2: avg, gumbel via rcp, GEMM2 =================
    float S24[4] = {0.f, 0.f, 0.f, 0.f};
    f32x4 acc2[4];
#pragma unroll
    for (int dt = 0; dt < 4; ++dt) acc2[dt] = (f32x4){0.f, 0.f, 0.f, 0.f};
    const int srcA = rh + 16 * ((2 * g) & 3);
    const int srcB = rh + 16 * ((2 * g + 1) & 3);
    const bool hi = (g & 2) != 0;

#pragma unroll
    for (int T = 0; T < 4; ++T) {
        // GEMM2 B loads (L2-resident)
        short8 cb2[8];
#pragma unroll
        for (int dt = 0; dt < 4; ++dt)
#pragma unroll
            for (int ks = 0; ks < 2; ++ks)
                cb2[2 * dt + ks] = *(const short8*)(cbNT +
                    (size_t)(rh + 16 * dt) * 512 + 256 * W + 64 * T + 32 * ks + 8 * g);

        // unpack e (bf16 -> f32)
        float ev[16];
#pragma unroll
        for (int k2 = 0; k2 < 8; ++k2) {
            const uint32_t pe = epk[8 * T + k2];
            ev[2 * k2] = __uint_as_float(pe << 16);
            ev[2 * k2 + 1] = __uint_as_float(pe & 0xffff0000u);
        }

        // gumbel: e2 = (e * rcp(-ln(u+eps)+eps))^2 (scales cancel in norm)
        float pf[8];
#pragma unroll
        for (int q = 0; q < 4; ++q) {
            const float uu[4] = {uN[T][q].x, uN[T][q].y, uN[T][q].z, uN[T][q].w};
            float e2v[4];
#pragma unroll
            for (int i = 0; i < 4; ++i) {
                const float lg = __builtin_amdgcn_logf(uu[i] + kEpsG);
                const float inr = fmaf(lg, -kLn2, kEpsG);
                const float r = __builtin_amdgcn_rcpf(inr);
                const float t = ev[4 * q + i] * r;
                const float e2 = t * t;
                e2v[i] = e2;
                S24[i] += e2;
            }
            pf[2 * q] = __uint_as_float(pk_bf16(e2v[0], e2v[1]));
            pf[2 * q + 1] = __uint_as_float(pk_bf16(e2v[2], e2v[3]));
        }

        // p = e*inv; butterfly transpose-reduce over 16 rows (destroys ev)
#pragma unroll
        for (int j = 0; j < 16; ++j) ev[j] *= inv;
#pragma unroll
        for (int m = 1, nv = 8; m <= 8; m <<= 1, nv >>= 1) {
            const bool up_ = (rh & m) != 0;
#pragma unroll
            for (int t = 0; t < nv; ++t) {
                const float a = ev[t], b = ev[t + nv];
                const float keep = up_ ? b : a;
                const float send = up_ ? a : b;
                ev[t] = keep + __shfl_xor(send, m, 64);
            }
        }
        const int jr = ((rh & 1) << 3) | ((rh & 2) << 1) | ((rh & 4) >> 1) |
                       ((rh & 8) >> 3);
        avg_lds[256 * W + 64 * T + 16 * (jr >> 2) + 4 * g + (jr & 3)] = ev[0];

        // D->A exchange + GEMM2
#pragma unroll
        for (int ks = 0; ks < 2; ++ks) {
            const float a0lo = __shfl(pf[4 * ks + 0], srcA, 64);
            const float a1lo = __shfl(pf[4 * ks + 1], srcA, 64);
            const float a0hi = __shfl(pf[4 * ks + 2], srcA, 64);
            const float a1hi = __shfl(pf[4 * ks + 3], srcA, 64);
            const float b0lo = __shfl(pf[4 * ks + 0], srcB, 64);
            const float b1lo = __shfl(pf[4 * ks + 1], srcB, 64);
            const float b0hi = __shfl(pf[4 * ks + 2], srcB, 64);
            const float b1hi = __shfl(pf[4 * ks + 3], srcB, 64);
            U8 af;
            af.u[0] = __float_as_uint(hi ? a0hi : a0lo);
            af.u[1] = __float_as_uint(hi ? a1hi : a1lo);
            af.u[2] = __float_as_uint(hi ? b0hi : b0lo);
            af.u[3] = __float_as_uint(hi ? b1hi : b1lo);
#pragma unroll
            for (int dt = 0; dt < 4; ++dt)
                acc2[dt] = __builtin_amdgcn_mfma_f32_16x16x32_bf16(
                    af.s, cb2[2 * dt + ks], acc2[dt], 0, 0, 0);
        }
    }

    // ---- merge S2 + exchange acc2 partials (single barrier)
    float S2r = (S24[0] + S24[1]) + (S24[2] + S24[3]);
    S2r += __shfl_xor(S2r, 16, 64);
    S2r += __shfl_xor(S2r, 32, 64);
    if (g == 0) cS2[W][rh] = S2r;
    if (W == 0) {
        accx[0][0][l] = make_float4(acc2[2][0], acc2[2][1], acc2[2][2], acc2[2][3]);
        accx[0][1][l] = make_float4(acc2[3][0], acc2[3][1], acc2[3][2], acc2[3][3]);
    } else {
        accx[1][0][l] = make_float4(acc2[0][0], acc2[0][1], acc2[0][2], acc2[0][3]);
        accx[1][1][l] = make_float4(acc2[1][0], acc2[1][1], acc2[1][2], acc2[1][3]);
    }
    __syncthreads();
    const float inv2 = 1.0f / (cS2[0][rh] + cS2[1][rh]);
    float ivi[4];
#pragma unroll
    for (int i = 0; i < 4; ++i) ivi[i] = __shfl(inv2, 4 * g + i, 64);

    float kldc = 0.f;
#define EPI(OV, XV, DT)                                                       \
    {                                                                         \
        const float oq[4] = {OV[0] + XV.x, OV[1] + XV.y, OV[2] + XV.z,        \
                             OV[3] + XV.w};                                   \
        _Pragma("unroll") for (int i = 0; i < 4; ++i) {                       \
            const float q = oq[i] * ivi[i];                                   \
            const size_t oi = (size_t)(r0 + 4 * g + i) * 64 + rh + 16 * (DT); \
            out[oi] = q;                                                      \
            const float zv = z[oi];                                           \
            kldc = fmaf(zv, zv - q, kldc);                                    \
        }                                                                     \
    }
    if (W == 0) {
        const float4 x0 = accx[1][0][l];
        const float4 x1 = accx[1][1][l];
        EPI(acc2[0], x0, 0)
        EPI(acc2[1], x1, 1)
    } else {
        const float4 x0 = accx[0][0][l];
        const float4 x1 = accx[0][1][l];
        EPI(acc2[2], x0, 2)
        EPI(acc2[3], x1, 3)
    }

    // ---- scalar + avg reductions (wave reductions before divergence)
    const int slot = blockIdx.x & (kSlots - 1);
    float* gp = g_part + (size_t)slot * kStride;
    const float kc = wsum64(kldc) * kq;
    const float kd = wsum64(kldd) * 0.25f;
    if (l == 0) {
        atomicAdd(&gp[513], kc);
        if (W == 0) atomicAdd(&gp[512], kd);
    }
    const float4 av = *(const float4*)&avg_lds[tid * 4];
    atomicAdd(&gp[tid * 4 + 0], av.x);
    atomicAdd(&gp[tid * 4 + 1], av.y);
    atomicAdd(&gp[tid * 4 + 2], av.z);
    atomicAdd(&gp[tid * 4 + 3], av.w);
}

__global__ __launch_bounds__(512) void k_final(const float* __restrict__ g_part,
                                               float* __restrict__ out) {
    __shared__ float red[8];
    const int tid = threadIdx.x;
    float sacc = 0.f;
#pragma unroll 8
    for (int i = 0; i < kSlots; ++i) sacc += g_part[(size_t)i * kStride + tid];
    const float avg = sacc * (1.0f / 65536.0f);
    const float t = avg * __logf(avg + kEpsP);
    const float sw = wsum64(t);
    if ((tid & 63) == 0) red[tid >> 6] = sw;
    __syncthreads();
    if (tid == 0) {
        float tot = 0.f;
#pragma unroll
        for (int i = 0; i < 8; ++i) tot += red[i];
        float sc0 = 0.f, sc1 = 0.f;
        for (int i = 0; i < kSlots; ++i) {
            sc0 += g_part[(size_t)i * kStride + 512];
            sc1 += g_part[(size_t)i * kStride + 513];
        }
        out[4194304] = (sc0 + sc1) * 0.125f;
        out[4194305] = __expf(-tot);
    }
}

extern "C" void kernel_launch(void* const* d_in, const int* in_sizes, int n_in,
                              void* d_out, int out_size, void* d_ws, size_t ws_size,
                              hipStream_t stream) {
    (void)in_sizes; (void)n_in; (void)out_size; (void)ws_size;
    const float* z   = (const float*)d_in[0];
    const float* kq  = (const float*)d_in[1];
    const float* cb  = (const float*)d_in[2];
    const float* gum = (const float*)d_in[3];
    float* out = (float*)d_out;

    uint16_t* cbN  = (uint16_t*)d_ws;
    uint16_t* cbNT = cbN + 32768;
    float* g_part  = (float*)(cbNT + 32768);

    (void)hipMemsetAsync(g_part, 0, kSlots * kStride * sizeof(float), stream);
    k_prep<<<128, 256, 0, stream>>>(cb, cbN, cbNT);
    k_main<<<4096, 128, 0, stream>>>(z, kq, gum, cbN, cbNT, out, g_part);
    k_final<<<1, 512, 0, stream>>>(g_part, out);
}

// Round 15
// 134.504 us; speedup vs baseline: 1.3128x; 1.3128x over previous
//
#include <hip/hip_runtime.h>
#include <cstdint>
#include <cstddef>

// VmfVectorQuantizer round 15: R9 champion structure (2 waves/16-row tile,
// 256 codes/wave, 4096x128) with launch_bounds(128,3) -> 170-reg budget,
// 3 waves/SIMD target (was 2). kSlots back to 128 (R14's 1024 made the
// single-block k_final a ~50us tail). 4-deep upfront u prefetch retained.

typedef __attribute__((ext_vector_type(8))) short short8;
typedef __attribute__((ext_vector_type(4))) float f32x4;

namespace {
constexpr float kEpsG = 1e-10f;
constexpr float kEpsN = 1e-12f;
constexpr float kEpsP = 1e-7f;
constexpr float kLog2e = 1.4426950408889634f;
constexpr float kLn2 = 0.6931471805599453f;
constexpr int kSlots = 128;
constexpr int kStride = 520;
}

__device__ __forceinline__ float wsum64(float v) {
#pragma unroll
    for (int m = 1; m < 64; m <<= 1) v += __shfl_xor(v, m, 64);
    return v;
}
__device__ __forceinline__ uint32_t pk_bf16(float a, float b) {
    uint32_t ua = __float_as_uint(a), ub = __float_as_uint(b);
    ua += 0x7fffu + ((ua >> 16) & 1u);
    ub += 0x7fffu + ((ub >> 16) & 1u);
    return (ua >> 16) | (ub & 0xffff0000u);
}
__device__ __forceinline__ uint16_t bf16_rne(float a) {
    uint32_t ua = __float_as_uint(a);
    ua += 0x7fffu + ((ua >> 16) & 1u);
    return (uint16_t)(ua >> 16);
}
__device__ __forceinline__ float dot4(float4 v) {
    return v.x * v.x + v.y * v.y + v.z * v.z + v.w * v.w;
}

__global__ __launch_bounds__(256) void k_prep(const float* __restrict__ cb,
                                              uint16_t* __restrict__ cbN,
                                              uint16_t* __restrict__ cbNT) {
    const int row = blockIdx.x * 4 + (threadIdx.x >> 6);
    const int lane = threadIdx.x & 63;
    const float v = cb[row * 64 + lane];
    const float ss = wsum64(v * v);
    const float nv = v / fmaxf(sqrtf(ss), kEpsN);
    const uint16_t h = bf16_rne(nv);
    cbN[row * 64 + lane] = h;
    cbNT[lane * 512 + row] = h;
}

// ---- k_main: 2 waves per 16-row tile; wave W owns codes [256W, 256W+256).
__global__ __launch_bounds__(128, 3) void k_main(
    const float* __restrict__ z, const float* __restrict__ kqp,
    const float* __restrict__ gum, const uint16_t* __restrict__ cbN,
    const uint16_t* __restrict__ cbNT, float* __restrict__ out,
    float* __restrict__ g_part) {
    __shared__ float avg_lds[512];
    __shared__ float cS[2][16], cW[2][16], cS2[2][16];
    __shared__ float4 accx[2][2][64];

    const int tid = threadIdx.x;
    const int W = tid >> 6;
    const int l = tid & 63;
    const int g = l >> 4;
    const int rh = l & 15;
    const int r0 = blockIdx.x * 16;
    const int row = r0 + rh;
    const float kq = *kqp;

    // ---- z load + L2 normalize; fold kq*log2e into bf16 B-fragments
    const float* zr = z + (size_t)row * 64;
    const float4 a0 = *(const float4*)(zr + 8 * g);
    const float4 a1 = *(const float4*)(zr + 8 * g + 4);
    const float4 a2 = *(const float4*)(zr + 32 + 8 * g);
    const float4 a3 = *(const float4*)(zr + 36 + 8 * g);
    float ss = dot4(a0) + dot4(a1) + dot4(a2) + dot4(a3);
    ss += __shfl_xor(ss, 16, 64);
    ss += __shfl_xor(ss, 32, 64);
    const float scz = kq * kLog2e / fmaxf(sqrtf(ss), kEpsN);
    union U8 { short8 s; uint32_t u[4]; };
    U8 zb0, zb1;
    zb0.u[0] = pk_bf16(a0.x * scz, a0.y * scz);
    zb0.u[1] = pk_bf16(a0.z * scz, a0.w * scz);
    zb0.u[2] = pk_bf16(a1.x * scz, a1.y * scz);
    zb0.u[3] = pk_bf16(a1.z * scz, a1.w * scz);
    zb1.u[0] = pk_bf16(a2.x * scz, a2.y * scz);
    zb1.u[1] = pk_bf16(a2.z * scz, a2.w * scz);
    zb1.u[2] = pk_bf16(a3.x * scz, a3.y * scz);
    zb1.u[3] = pk_bf16(a3.z * scz, a3.w * scz);

    const float B1 = kq * kLog2e;  // static bound: x <= B1

    // ---- ALL 4 u tiles prefetched upfront (completes under pass 1)
    const float* ur = gum + (size_t)row * 512 + 256 * W;
    float4 uN[4][4];
#pragma unroll
    for (int t = 0; t < 4; ++t)
#pragma unroll
        for (int j = 0; j < 4; ++j)
            uN[t][j] = *(const float4*)(ur + 64 * t + 16 * j + 4 * g);

    const uint16_t* cbW = cbN + (size_t)(256 * W) * 64;

    // ================= pass 1: logits -> e (bf16-packed), S, W ============
    uint32_t epk[32];
    float S4[4] = {0.f, 0.f, 0.f, 0.f}, W4[4] = {0.f, 0.f, 0.f, 0.f};
#pragma unroll
    for (int T = 0; T < 4; ++T) {
        short8 ca[8];
#pragma unroll
        for (int q = 0; q < 4; ++q) {
            const uint16_t* cr = cbW + (size_t)((64 * T + 16 * q + rh) * 64);
            ca[2 * q] = *(const short8*)(cr + 8 * g);
            ca[2 * q + 1] = *(const short8*)(cr + 32 + 8 * g);
        }
#pragma unroll
        for (int q = 0; q < 4; ++q) {
            f32x4 acc = {0.f, 0.f, 0.f, 0.f};
            acc = __builtin_amdgcn_mfma_f32_16x16x32_bf16(ca[2 * q], zb0.s, acc, 0, 0, 0);
            acc = __builtin_amdgcn_mfma_f32_16x16x32_bf16(ca[2 * q + 1], zb1.s, acc, 0, 0, 0);
            float e4[4];
#pragma unroll
            for (int i = 0; i < 4; ++i) {
                const float d = acc[i] - B1;
                const float e = __builtin_amdgcn_exp2f(d);
                e4[i] = e;
                S4[i] += e;
                W4[i] = fmaf(d, e, W4[i]);
            }
            epk[8 * T + 2 * q] = pk_bf16(e4[0], e4[1]);
            epk[8 * T + 2 * q + 1] = pk_bf16(e4[2], e4[3]);
        }
    }
    float Sr = (S4[0] + S4[1]) + (S4[2] + S4[3]);
    float Wr = (W4[0] + W4[1]) + (W4[2] + W4[3]);
    Sr += __shfl_xor(Sr, 16, 64);
    Sr += __shfl_xor(Sr, 32, 64);
    Wr += __shfl_xor(Wr, 16, 64);
    Wr += __shfl_xor(Wr, 32, 64);
    if (g == 0) { cS[W][rh] = Sr; cW[W][rh] = Wr; }
    __syncthreads();
    const float St = cS[0][rh] + cS[1][rh];
    const float Wt = cW[0][rh] + cW[1][rh];
    const float inv = 1.0f / St;
    const float kldd = kLn2 * (Wt * inv - __builtin_amdgcn_logf(St));

    // ================= pass 2: avg, gumbel via rcp, GEMM2 =================
    float S24[4] = {0.f, 0.f, 0.f, 0.f};
    f32x4 acc2[4];
#pragma unroll
    for (int dt = 0; dt < 4; ++dt) acc2[dt] = (f32x4){0.f, 0.f, 0.f, 0.f};
    const int srcA = rh + 16 * ((2 * g) & 3);
    const int srcB = rh + 16 * ((2 * g + 1) & 3);
    const bool hi = (g & 2) != 0;

#pragma unroll
    for (int T = 0; T < 4; ++T) {
        // GEMM2 B loads (L2-resident)
        short8 cb2[8];
#pragma unroll
        for (int dt = 0; dt < 4; ++dt)
#pragma unroll
            for (int ks = 0; ks < 2; ++ks)
                cb2[2 * dt + ks] = *(const short8*)(cbNT +
                    (size_t)(rh + 16 * dt) * 512 + 256 * W + 64 * T + 32 * ks + 8 * g);

        // unpack e (bf16 -> f32)
        float ev[16];
#pragma unroll
        for (int k2 = 0; k2 < 8; ++k2) {
            const uint32_t pe = epk[8 * T + k2];
            ev[2 * k2] = __uint_as_float(pe << 16);
            ev[2 * k2 + 1] = __uint_as_float(pe & 0xffff0000u);
        }

        // gumbel: e2 = (e * rcp(-ln(u+eps)+eps))^2 (scales cancel in norm)
        float pf[8];
#pragma unroll
        for (int q = 0; q < 4; ++q) {
            const float uu[4] = {uN[T][q].x, uN[T][q].y, uN[T][q].z, uN[T][q].w};
            float e2v[4];
#pragma unroll
            for (int i = 0; i < 4; ++i) {
                const float lg = __builtin_amdgcn_logf(uu[i] + kEpsG);
                const float inr = fmaf(lg, -kLn2, kEpsG);
                const float r = __builtin_amdgcn_rcpf(inr);
                const float t = ev[4 * q + i] * r;
                const float e2 = t * t;
                e2v[i] = e2;
                S24[i] += e2;
            }
            pf[2 * q] = __uint_as_float(pk_bf16(e2v[0], e2v[1]));
            pf[2 * q + 1] = __uint_as_float(pk_bf16(e2v[2], e2v[3]));
        }

        // p = e*inv; butterfly transpose-reduce over 16 rows (destroys ev)
#pragma unroll
        for (int j = 0; j < 16; ++j) ev[j] *= inv;
#pragma unroll
        for (int m = 1, nv = 8; m <= 8; m <<= 1, nv >>= 1) {
            const bool up_ = (rh & m) != 0;
#pragma unroll
            for (int t = 0; t < nv; ++t) {
                const float a = ev[t], b = ev[t + nv];
                const float keep = up_ ? b : a;
                const float send = up_ ? a : b;
                ev[t] = keep + __shfl_xor(send, m, 64);
            }
        }
        const int jr = ((rh & 1) << 3) | ((rh & 2) << 1) | ((rh & 4) >> 1) |
                       ((rh & 8) >> 3);
        avg_lds[256 * W + 64 * T + 16 * (jr >> 2) + 4 * g + (jr & 3)] = ev[0];

        // D->A exchange + GEMM2
#pragma unroll
        for (int ks = 0; ks < 2; ++ks) {
            const float a0lo = __shfl(pf[4 * ks + 0], srcA, 64);
            const float a1lo = __shfl(pf[4 * ks + 1], srcA, 64);
            const float a0hi = __shfl(pf[4 * ks + 2], srcA, 64);
            const float a1hi = __shfl(pf[4 * ks + 3], srcA, 64);
            const float b0lo = __shfl(pf[4 * ks + 0], srcB, 64);
            const float b1lo = __shfl(pf[4 * ks + 1], srcB, 64);
            const float b0hi = __shfl(pf[4 * ks + 2], srcB, 64);
            const float b1hi = __shfl(pf[4 * ks + 3], srcB, 64);
            U8 af;
            af.u[0] = __float_as_uint(hi ? a0hi : a0lo);
            af.u[1] = __float_as_uint(hi ? a1hi : a1lo);
            af.u[2] = __float_as_uint(hi ? b0hi : b0lo);
            af.u[3] = __float_as_uint(hi ? b1hi : b1lo);
#pragma unroll
            for (int dt = 0; dt < 4; ++dt)
                acc2[dt] = __builtin_amdgcn_mfma_f32_16x16x32_bf16(
                    af.s, cb2[2 * dt + ks], acc2[dt], 0, 0, 0);
        }
    }

    // ---- merge S2 + exchange acc2 partials (single barrier)
    float S2r = (S24[0] + S24[1]) + (S24[2] + S24[3]);
    S2r += __shfl_xor(S2r, 16, 64);
    S2r += __shfl_xor(S2r, 32, 64);
    if (g == 0) cS2[W][rh] = S2r;
    if (W == 0) {
        accx[0][0][l] = make_float4(acc2[2][0], acc2[2][1], acc2[2][2], acc2[2][3]);
        accx[0][1][l] = make_float4(acc2[3][0], acc2[3][1], acc2[3][2], acc2[3][3]);
    } else {
        accx[1][0][l] = make_float4(acc2[0][0], acc2[0][1], acc2[0][2], acc2[0][3]);
        accx[1][1][l] = make_float4(acc2[1][0], acc2[1][1], acc2[1][2], acc2[1][3]);
    }
    __syncthreads();
    const float inv2 = 1.0f / (cS2[0][rh] + cS2[1][rh]);
    float ivi[4];
#pragma unroll
    for (int i = 0; i < 4; ++i) ivi[i] = __shfl(inv2, 4 * g + i, 64);

    float kldc = 0.f;
#define EPI(OV, XV, DT)                                                       \
    {                                                                         \
        const float oq[4] = {OV[0] + XV.x, OV[1] + XV.y, OV[2] + XV.z,        \
                             OV[3] + XV.w};                                   \
        _Pragma("unroll") for (int i = 0; i < 4; ++i) {                       \
            const float q = oq[i] * ivi[i];                                   \
            const size_t oi = (size_t)(r0 + 4 * g + i) * 64 + rh + 16 * (DT); \
            out[oi] = q;                                                      \
            const float zv = z[oi];                                           \
            kldc = fmaf(zv, zv - q, kldc);                                    \
        }                                                                     \
    }
    if (W == 0) {
        const float4 x0 = accx[1][0][l];
        const float4 x1 = accx[1][1][l];
        EPI(acc2[0], x0, 0)
        EPI(acc2[1], x1, 1)
    } else {
        const float4 x0 = accx[0][0][l];
        const float4 x1 = accx[0][1][l];
        EPI(acc2[2], x0, 2)
        EPI(acc2[3], x1, 3)
    }

    // ---- scalar + avg reductions (wave reductions before divergence)
    const int slot = blockIdx.x & (kSlots - 1);
    float* gp = g_part + (size_t)slot * kStride;
    const float kc = wsum64(kldc) * kq;
    const float kd = wsum64(kldd) * 0.25f;
    if (l == 0) {
        atomicAdd(&gp[513], kc);
        if (W == 0) atomicAdd(&gp[512], kd);
    }
    const float4 av = *(const float4*)&avg_lds[tid * 4];
    atomicAdd(&gp[tid * 4 + 0], av.x);
    atomicAdd(&gp[tid * 4 + 1], av.y);
    atomicAdd(&gp[tid * 4 + 2], av.z);
    atomicAdd(&gp[tid * 4 + 3], av.w);
}

__global__ __launch_bounds__(512) void k_final(const float* __restrict__ g_part,
                                               float* __restrict__ out) {
    __shared__ float red[8];
    const int tid = threadIdx.x;
    float sacc = 0.f;
#pragma unroll 8
    for (int i = 0; i < kSlots; ++i) sacc += g_part[(size_t)i * kStride + tid];
    const float avg = sacc * (1.0f / 65536.0f);
    const float t = avg * __logf(avg + kEpsP);
    const float sw = wsum64(t);
    if ((tid & 63) == 0) red[tid >> 6] = sw;
    __syncthreads();
    if (tid == 0) {
        float tot = 0.f;
#pragma unroll
        for (int i = 0; i < 8; ++i) tot += red[i];
        float sc0 = 0.f, sc1 = 0.f;
        for (int i = 0; i < kSlots; ++i) {
            sc0 += g_part[(size_t)i * kStride + 512];
            sc1 += g_part[(size_t)i * kStride + 513];
        }
        out[4194304] = (sc0 + sc1) * 0.125f;
        out[4194305] = __expf(-tot);
    }
}

extern "C" void kernel_launch(void* const* d_in, const int* in_sizes, int n_in,
                              void* d_out, int out_size, void* d_ws, size_t ws_size,
                              hipStream_t stream) {
    (void)in_sizes; (void)n_in; (void)out_size; (void)ws_size;
    const float* z   = (const float*)d_in[0];
    const float* kq  = (const float*)d_in[1];
    const float* cb  = (const float*)d_in[2];
    const float* gum = (const float*)d_in[3];
    float* out = (float*)d_out;

    uint16_t* cbN  = (uint16_t*)d_ws;
    uint16_t* cbNT = cbN + 32768;
    float* g_part  = (float*)(cbNT + 32768);

    (void)hipMemsetAsync(g_part, 0, kSlots * kStride * sizeof(float), stream);
    k_prep<<<128, 256, 0, stream>>>(cb, cbN, cbNT);
    k_main<<<4096, 128, 0, stream>>>(z, kq, gum, cbN, cbNT, out, g_part);
    k_final<<<1, 512, 0, stream>>>(g_part, out);
}

// Round 16
// 118.564 us; speedup vs baseline: 1.4893x; 1.1344x over previous
//
#include <hip/hip_runtime.h>
#include <cstdint>
#include <cstddef>

// VmfVectorQuantizer round 16: R9 champion structure (2 waves/16-row tile,
// 256 codes/wave) with 48+ regs of state removed so launch_bounds(128,3)
// holds WITHOUT spill: u-prefetch 64->32 regs (ping-pong buffers), pass-1
// ca[] and pass-2 cb2[] staging inlined into the MFMA loops (R12 form).

typedef __attribute__((ext_vector_type(8))) short short8;
typedef __attribute__((ext_vector_type(4))) float f32x4;

namespace {
constexpr float kEpsG = 1e-10f;
constexpr float kEpsN = 1e-12f;
constexpr float kEpsP = 1e-7f;
constexpr float kLog2e = 1.4426950408889634f;
constexpr float kLn2 = 0.6931471805599453f;
constexpr int kSlots = 128;
constexpr int kStride = 520;
}

__device__ __forceinline__ float wsum64(float v) {
#pragma unroll
    for (int m = 1; m < 64; m <<= 1) v += __shfl_xor(v, m, 64);
    return v;
}
__device__ __forceinline__ uint32_t pk_bf16(float a, float b) {
    uint32_t ua = __float_as_uint(a), ub = __float_as_uint(b);
    ua += 0x7fffu + ((ua >> 16) & 1u);
    ub += 0x7fffu + ((ub >> 16) & 1u);
    return (ua >> 16) | (ub & 0xffff0000u);
}
__device__ __forceinline__ uint16_t bf16_rne(float a) {
    uint32_t ua = __float_as_uint(a);
    ua += 0x7fffu + ((ua >> 16) & 1u);
    return (uint16_t)(ua >> 16);
}
__device__ __forceinline__ float dot4(float4 v) {
    return v.x * v.x + v.y * v.y + v.z * v.z + v.w * v.w;
}

__global__ __launch_bounds__(256) void k_prep(const float* __restrict__ cb,
                                              uint16_t* __restrict__ cbN,
                                              uint16_t* __restrict__ cbNT) {
    const int row = blockIdx.x * 4 + (threadIdx.x >> 6);
    const int lane = threadIdx.x & 63;
    const float v = cb[row * 64 + lane];
    const float ss = wsum64(v * v);
    const float nv = v / fmaxf(sqrtf(ss), kEpsN);
    const uint16_t h = bf16_rne(nv);
    cbN[row * 64 + lane] = h;
    cbNT[lane * 512 + row] = h;
}

// ---- k_main: 2 waves per 16-row tile; wave W owns codes [256W, 256W+256).
__global__ __launch_bounds__(128, 3) void k_main(
    const float* __restrict__ z, const float* __restrict__ kqp,
    const float* __restrict__ gum, const uint16_t* __restrict__ cbN,
    const uint16_t* __restrict__ cbNT, float* __restrict__ out,
    float* __restrict__ g_part) {
    __shared__ float avg_lds[512];
    __shared__ float cS[2][16], cW[2][16], cS2[2][16];
    __shared__ float4 accx[2][2][64];

    const int tid = threadIdx.x;
    const int W = tid >> 6;
    const int l = tid & 63;
    const int g = l >> 4;
    const int rh = l & 15;
    const int r0 = blockIdx.x * 16;
    const int row = r0 + rh;
    const float kq = *kqp;

    // ---- z load + L2 normalize; fold kq*log2e into bf16 B-fragments
    const float* zr = z + (size_t)row * 64;
    const float4 a0 = *(const float4*)(zr + 8 * g);
    const float4 a1 = *(const float4*)(zr + 8 * g + 4);
    const float4 a2 = *(const float4*)(zr + 32 + 8 * g);
    const float4 a3 = *(const float4*)(zr + 36 + 8 * g);
    float ss = dot4(a0) + dot4(a1) + dot4(a2) + dot4(a3);
    ss += __shfl_xor(ss, 16, 64);
    ss += __shfl_xor(ss, 32, 64);
    const float scz = kq * kLog2e / fmaxf(sqrtf(ss), kEpsN);
    union U8 { short8 s; uint32_t u[4]; };
    U8 zb0, zb1;
    zb0.u[0] = pk_bf16(a0.x * scz, a0.y * scz);
    zb0.u[1] = pk_bf16(a0.z * scz, a0.w * scz);
    zb0.u[2] = pk_bf16(a1.x * scz, a1.y * scz);
    zb0.u[3] = pk_bf16(a1.z * scz, a1.w * scz);
    zb1.u[0] = pk_bf16(a2.x * scz, a2.y * scz);
    zb1.u[1] = pk_bf16(a2.z * scz, a2.w * scz);
    zb1.u[2] = pk_bf16(a3.x * scz, a3.y * scz);
    zb1.u[3] = pk_bf16(a3.z * scz, a3.w * scz);

    const float B1 = kq * kLog2e;  // static bound: x <= B1

    // ---- u tile 0 prefetch into buffer A (hides under pass 1)
    const float* ur = gum + (size_t)row * 512 + 256 * W;
    float4 uA[4], uB[4];
#pragma unroll
    for (int j = 0; j < 4; ++j) uA[j] = *(const float4*)(ur + 16 * j + 4 * g);

    const uint16_t* cbW = cbN + (size_t)(256 * W) * 64;

    // ================= pass 1: logits -> e (bf16-packed), S, W ============
    uint32_t epk[32];
    float S4[4] = {0.f, 0.f, 0.f, 0.f}, W4[4] = {0.f, 0.f, 0.f, 0.f};
#pragma unroll
    for (int T = 0; T < 4; ++T) {
#pragma unroll
        for (int q = 0; q < 4; ++q) {
            const uint16_t* cr = cbW + (size_t)((64 * T + 16 * q + rh) * 64);
            const short8 ca0 = *(const short8*)(cr + 8 * g);
            const short8 ca1 = *(const short8*)(cr + 32 + 8 * g);
            f32x4 acc = {0.f, 0.f, 0.f, 0.f};
            acc = __builtin_amdgcn_mfma_f32_16x16x32_bf16(ca0, zb0.s, acc, 0, 0, 0);
            acc = __builtin_amdgcn_mfma_f32_16x16x32_bf16(ca1, zb1.s, acc, 0, 0, 0);
            float e4[4];
#pragma unroll
            for (int i = 0; i < 4; ++i) {
                const float d = acc[i] - B1;
                const float e = __builtin_amdgcn_exp2f(d);
                e4[i] = e;
                S4[i] += e;
                W4[i] = fmaf(d, e, W4[i]);
            }
            epk[8 * T + 2 * q] = pk_bf16(e4[0], e4[1]);
            epk[8 * T + 2 * q + 1] = pk_bf16(e4[2], e4[3]);
        }
    }
    float Sr = (S4[0] + S4[1]) + (S4[2] + S4[3]);
    float Wr = (W4[0] + W4[1]) + (W4[2] + W4[3]);
    Sr += __shfl_xor(Sr, 16, 64);
    Sr += __shfl_xor(Sr, 32, 64);
    Wr += __shfl_xor(Wr, 16, 64);
    Wr += __shfl_xor(Wr, 32, 64);
    if (g == 0) { cS[W][rh] = Sr; cW[W][rh] = Wr; }
    // issue u tile 1 into buffer B; latency overlaps the barrier wait
#pragma unroll
    for (int j = 0; j < 4; ++j)
        uB[j] = *(const float4*)(ur + 64 + 16 * j + 4 * g);
    __syncthreads();
    const float St = cS[0][rh] + cS[1][rh];
    const float Wt = cW[0][rh] + cW[1][rh];
    const float inv = 1.0f / St;
    const float kldd = kLn2 * (Wt * inv - __builtin_amdgcn_logf(St));

    // ================= pass 2: avg, gumbel via rcp, GEMM2 =================
    float S24[4] = {0.f, 0.f, 0.f, 0.f};
    f32x4 acc2[4];
#pragma unroll
    for (int dt = 0; dt < 4; ++dt) acc2[dt] = (f32x4){0.f, 0.f, 0.f, 0.f};
    const int srcA = rh + 16 * ((2 * g) & 3);
    const int srcB = rh + 16 * ((2 * g + 1) & 3);
    const bool hi = (g & 2) != 0;

#define RELOAD(UB, RT)                                                       \
    _Pragma("unroll") for (int j = 0; j < 4; ++j)                            \
        UB[j] = *(const float4*)(ur + 64 * (RT) + 16 * j + 4 * g);

#define P2TILE(T, UB, PRE)                                                   \
    {                                                                        \
        float ev[16];                                                        \
        _Pragma("unroll") for (int k2 = 0; k2 < 8; ++k2) {                   \
            const uint32_t pe = epk[8 * (T) + k2];                           \
            ev[2 * k2] = __uint_as_float(pe << 16);                          \
            ev[2 * k2 + 1] = __uint_as_float(pe & 0xffff0000u);              \
        }                                                                    \
        float pf[8];                                                         \
        _Pragma("unroll") for (int q = 0; q < 4; ++q) {                      \
            const float uu[4] = {UB[q].x, UB[q].y, UB[q].z, UB[q].w};        \
            float e2v[4];                                                    \
            _Pragma("unroll") for (int i = 0; i < 4; ++i) {                  \
                const float lg = __builtin_amdgcn_logf(uu[i] + kEpsG);       \
                const float inr = fmaf(lg, -kLn2, kEpsG);                    \
                const float r = __builtin_amdgcn_rcpf(inr);                  \
                const float t = ev[4 * q + i] * r;                           \
                const float e2 = t * t;                                      \
                e2v[i] = e2;                                                 \
                S24[i] += e2;                                                \
            }                                                                \
            pf[2 * q] = __uint_as_float(pk_bf16(e2v[0], e2v[1]));            \
            pf[2 * q + 1] = __uint_as_float(pk_bf16(e2v[2], e2v[3]));        \
        }                                                                    \
        PRE                                                                  \
        _Pragma("unroll") for (int j = 0; j < 16; ++j) ev[j] *= inv;         \
        _Pragma("unroll") for (int m = 1, nv = 8; m <= 8; m <<= 1, nv >>= 1) \
        {                                                                    \
            const bool up_ = (rh & m) != 0;                                  \
            _Pragma("unroll") for (int t = 0; t < nv; ++t) {                 \
                const float a_ = ev[t], b_ = ev[t + nv];                     \
                const float keep = up_ ? b_ : a_;                            \
                const float send = up_ ? a_ : b_;                            \
                ev[t] = keep + __shfl_xor(send, m, 64);                      \
            }                                                                \
        }                                                                    \
        const int jr = ((rh & 1) << 3) | ((rh & 2) << 1) | ((rh & 4) >> 1) | \
                       ((rh & 8) >> 3);                                      \
        avg_lds[256 * W + 64 * (T) + 16 * (jr >> 2) + 4 * g + (jr & 3)] =    \
            ev[0];                                                           \
        _Pragma("unroll") for (int ks = 0; ks < 2; ++ks) {                   \
            const float a0lo = __shfl(pf[4 * ks + 0], srcA, 64);             \
            const float a1lo = __shfl(pf[4 * ks + 1], srcA, 64);             \
            const float a0hi = __shfl(pf[4 * ks + 2], srcA, 64);             \
            const float a1hi = __shfl(pf[4 * ks + 3], srcA, 64);             \
            const float b0lo = __shfl(pf[4 * ks + 0], srcB, 64);             \
            const float b1lo = __shfl(pf[4 * ks + 1], srcB, 64);             \
            const float b0hi = __shfl(pf[4 * ks + 2], srcB, 64);             \
            const float b1hi = __shfl(pf[4 * ks + 3], srcB, 64);             \
            U8 af;                                                           \
            af.u[0] = __float_as_uint(hi ? a0hi : a0lo);                     \
            af.u[1] = __float_as_uint(hi ? a1hi : a1lo);                     \
            af.u[2] = __float_as_uint(hi ? b0hi : b0lo);                     \
            af.u[3] = __float_as_uint(hi ? b1hi : b1lo);                     \
            _Pragma("unroll") for (int dt = 0; dt < 4; ++dt) {               \
                const short8 bf = *(const short8*)(cbNT +                    \
                    (size_t)(rh + 16 * dt) * 512 + 256 * W + 64 * (T) +      \
                    32 * ks + 8 * g);                                        \
                acc2[dt] = __builtin_amdgcn_mfma_f32_16x16x32_bf16(          \
                    af.s, bf, acc2[dt], 0, 0, 0);                            \
            }                                                                \
        }                                                                    \
    }

    P2TILE(0, uA, RELOAD(uA, 2))
    P2TILE(1, uB, RELOAD(uB, 3))
    P2TILE(2, uA, ;)
    P2TILE(3, uB, ;)

    // ---- merge S2 + exchange acc2 partials (single barrier)
    float S2r = (S24[0] + S24[1]) + (S24[2] + S24[3]);
    S2r += __shfl_xor(S2r, 16, 64);
    S2r += __shfl_xor(S2r, 32, 64);
    if (g == 0) cS2[W][rh] = S2r;
    if (W == 0) {
        accx[0][0][l] = make_float4(acc2[2][0], acc2[2][1], acc2[2][2], acc2[2][3]);
        accx[0][1][l] = make_float4(acc2[3][0], acc2[3][1], acc2[3][2], acc2[3][3]);
    } else {
        accx[1][0][l] = make_float4(acc2[0][0], acc2[0][1], acc2[0][2], acc2[0][3]);
        accx[1][1][l] = make_float4(acc2[1][0], acc2[1][1], acc2[1][2], acc2[1][3]);
    }
    __syncthreads();
    const float inv2 = 1.0f / (cS2[0][rh] + cS2[1][rh]);
    float ivi[4];
#pragma unroll
    for (int i = 0; i < 4; ++i) ivi[i] = __shfl(inv2, 4 * g + i, 64);

    float kldc = 0.f;
#define EPI(OV, XV, DT)                                                       \
    {                                                                         \
        const float oq[4] = {OV[0] + XV.x, OV[1] + XV.y, OV[2] + XV.z,        \
                             OV[3] + XV.w};                                   \
        _Pragma("unroll") for (int i = 0; i < 4; ++i) {                       \
            const float q = oq[i] * ivi[i];                                   \
            const size_t oi = (size_t)(r0 + 4 * g + i) * 64 + rh + 16 * (DT); \
            out[oi] = q;                                                      \
            const float zv = z[oi];                                           \
            kldc = fmaf(zv, zv - q, kldc);                                    \
        }                                                                     \
    }
    if (W == 0) {
        const float4 x0 = accx[1][0][l];
        const float4 x1 = accx[1][1][l];
        EPI(acc2[0], x0, 0)
        EPI(acc2[1], x1, 1)
    } else {
        const float4 x0 = accx[0][0][l];
        const float4 x1 = accx[0][1][l];
        EPI(acc2[2], x0, 2)
        EPI(acc2[3], x1, 3)
    }

    // ---- scalar + avg reductions (wave reductions before divergence)
    const int slot = blockIdx.x & (kSlots - 1);
    float* gp = g_part + (size_t)slot * kStride;
    const float kc = wsum64(kldc) * kq;
    const float kd = wsum64(kldd) * 0.25f;
    if (l == 0) {
        atomicAdd(&gp[513], kc);
        if (W == 0) atomicAdd(&gp[512], kd);
    }
    const float4 av = *(const float4*)&avg_lds[tid * 4];
    atomicAdd(&gp[tid * 4 + 0], av.x);
    atomicAdd(&gp[tid * 4 + 1], av.y);
    atomicAdd(&gp[tid * 4 + 2], av.z);
    atomicAdd(&gp[tid * 4 + 3], av.w);
}

__global__ __launch_bounds__(512) void k_final(const float* __restrict__ g_part,
                                               float* __restrict__ out) {
    __shared__ float red[8];
    const int tid = threadIdx.x;
    float sacc = 0.f;
#pragma unroll 8
    for (int i = 0; i < kSlots; ++i) sacc += g_part[(size_t)i * kStride + tid];
    const float avg = sacc * (1.0f / 65536.0f);
    const float t = avg * __logf(avg + kEpsP);
    const float sw = wsum64(t);
    if ((tid & 63) == 0) red[tid >> 6] = sw;
    __syncthreads();
    if (tid == 0) {
        float tot = 0.f;
#pragma unroll
        for (int i = 0; i < 8; ++i) tot += red[i];
        float sc0 = 0.f, sc1 = 0.f;
        for (int i = 0; i < kSlots; ++i) {
            sc0 += g_part[(size_t)i * kStride + 512];
            sc1 += g_part[(size_t)i * kStride + 513];
        }
        out[4194304] = (sc0 + sc1) * 0.125f;
        out[4194305] = __expf(-tot);
    }
}

extern "C" void kernel_launch(void* const* d_in, const int* in_sizes, int n_in,
                              void* d_out, int out_size, void* d_ws, size_t ws_size,
                              hipStream_t stream) {
    (void)in_sizes; (void)n_in; (void)out_size; (void)ws_size;
    const float* z   = (const float*)d_in[0];
    const float* kq  = (const float*)d_in[1];
    const float* cb  = (const float*)d_in[2];
    const float* gum = (const float*)d_in[3];
    float* out = (float*)d_out;

    uint16_t* cbN  = (uint16_t*)d_ws;
    uint16_t* cbNT = cbN + 32768;
    float* g_part  = (float*)(cbNT + 32768);

    (void)hipMemsetAsync(g_part, 0, kSlots * kStride * sizeof(float), stream);
    k_prep<<<128, 256, 0, stream>>>(cb, cbN, cbNT);
    k_main<<<4096, 128, 0, stream>>>(z, kq, gum, cbN, cbNT, out, g_part);
    k_final<<<1, 512, 0, stream>>>(g_part, out);
}

// Round 17
// 86.626 us; speedup vs baseline: 2.0384x; 1.3687x over previous
//
#include <hip/hip_runtime.h>
#include <cstdint>
#include <cstddef>

// VmfVectorQuantizer round 17: LDS-staged codebook. Every prior round
// re-read the 128 KB codebook from L2 per wave (1 GB L2 traffic/dispatch) —
// the invariant cost behind the 117 us plateau. Now: 512-thread blocks
// (8 waves = 4 tile-pairs of the verified R9 2-wave structure) stage both
// codebook layouts into LDS once (XOR-swizzled, 2-way-conflict-free) and
// all GEMM operand reads become ds_read_b128.

typedef __attribute__((ext_vector_type(8))) short short8;
typedef __attribute__((ext_vector_type(4))) float f32x4;

namespace {
constexpr float kEpsG = 1e-10f;
constexpr float kEpsN = 1e-12f;
constexpr float kEpsP = 1e-7f;
constexpr float kLog2e = 1.4426950408889634f;
constexpr float kLn2 = 0.6931471805599453f;
constexpr int kSlots = 128;
constexpr int kStride = 520;
// dynamic LDS layout (bytes)
constexpr int kOffCbn = 0;        // [512][64] bf16 swizzled      65536
constexpr int kOffCbt = 65536;    // [64][512] bf16 swizzled      65536
constexpr int kOffAvg = 131072;   // float [4][512]                8192
constexpr int kOffCS  = 139264;   // float [4][2][16] x3           1536
constexpr int kOffAcx = 140800;   // float4 [4][2][2][64]         16384
constexpr int kLdsBytes = 157184;
}

__device__ __forceinline__ float wsum64(float v) {
#pragma unroll
    for (int m = 1; m < 64; m <<= 1) v += __shfl_xor(v, m, 64);
    return v;
}
__device__ __forceinline__ uint32_t pk_bf16(float a, float b) {
    uint32_t ua = __float_as_uint(a), ub = __float_as_uint(b);
    ua += 0x7fffu + ((ua >> 16) & 1u);
    ub += 0x7fffu + ((ub >> 16) & 1u);
    return (ua >> 16) | (ub & 0xffff0000u);
}
__device__ __forceinline__ uint16_t bf16_rne(float a) {
    uint32_t ua = __float_as_uint(a);
    ua += 0x7fffu + ((ua >> 16) & 1u);
    return (uint16_t)(ua >> 16);
}
__device__ __forceinline__ float dot4(float4 v) {
    return v.x * v.x + v.y * v.y + v.z * v.z + v.w * v.w;
}

__global__ __launch_bounds__(256) void k_prep(const float* __restrict__ cb,
                                              uint16_t* __restrict__ cbN,
                                              uint16_t* __restrict__ cbNT) {
    const int row = blockIdx.x * 4 + (threadIdx.x >> 6);
    const int lane = threadIdx.x & 63;
    const float v = cb[row * 64 + lane];
    const float ss = wsum64(v * v);
    const float nv = v / fmaxf(sqrtf(ss), kEpsN);
    const uint16_t h = bf16_rne(nv);
    cbN[row * 64 + lane] = h;
    cbNT[lane * 512 + row] = h;
}

// ---- k_main: 1024 blocks x 512 threads (8 waves = 4 tile-pairs).
// Tile-pair tp covers rows [blk*64 + 16tp, +16); wave W in pair owns codes
// [256W, 256W+256). Codebook served from swizzled LDS.
__global__ __launch_bounds__(512, 2) void k_main(
    const float* __restrict__ z, const float* __restrict__ kqp,
    const float* __restrict__ gum, const uint16_t* __restrict__ cbN,
    const uint16_t* __restrict__ cbNT, float* __restrict__ out,
    float* __restrict__ g_part) {
    extern __shared__ float4 smem_al[];
    char* smem = (char*)smem_al;
    float* avg4 = (float*)(smem + kOffAvg);
    float (*cS)[2][16]  = (float(*)[2][16])(smem + kOffCS);
    float (*cW)[2][16]  = (float(*)[2][16])(smem + kOffCS + 512);
    float (*cS2)[2][16] = (float(*)[2][16])(smem + kOffCS + 1024);
    float4 (*accx)[2][2][64] = (float4(*)[2][2][64])(smem + kOffAcx);

    const int tid = threadIdx.x;
    const int wv = tid >> 6;   // 0..7
    const int tp = wv >> 1;    // tile-pair 0..3
    const int W = wv & 1;      // code-half
    const int l = tid & 63;
    const int g = l >> 4;
    const int rh = l & 15;
    const int r0 = blockIdx.x * 64 + tp * 16;
    const int row = r0 + rh;
    const float kq = *kqp;

    // ---- stage codebook into swizzled LDS (coalesced 16B chunks) ----
#pragma unroll
    for (int it = 0; it < 16; ++it) {
        const int i = tid + 512 * it;          // chunk id, 8192 total
        const uint4 v = ((const uint4*)cbN)[i];
        const int r = i >> 3, c = i & 7;
        *(uint4*)(smem + r * 128 + (((c ^ (r & 7))) << 4)) = v;
    }
#pragma unroll
    for (int it = 0; it < 8; ++it) {
        const int i = tid + 512 * it;          // chunk id, 4096 total
        const uint4 v = ((const uint4*)cbNT)[i];
        const int d = i >> 6, c = i & 63;
        *(uint4*)(smem + kOffCbt + d * 1024 + ((c ^ (d & 7)) << 4)) = v;
    }

    // ---- z load + L2 normalize; fold kq*log2e into bf16 B-fragments
    const float* zr = z + (size_t)row * 64;
    const float4 a0 = *(const float4*)(zr + 8 * g);
    const float4 a1 = *(const float4*)(zr + 8 * g + 4);
    const float4 a2 = *(const float4*)(zr + 32 + 8 * g);
    const float4 a3 = *(const float4*)(zr + 36 + 8 * g);
    float ss = dot4(a0) + dot4(a1) + dot4(a2) + dot4(a3);
    ss += __shfl_xor(ss, 16, 64);
    ss += __shfl_xor(ss, 32, 64);
    const float scz = kq * kLog2e / fmaxf(sqrtf(ss), kEpsN);
    union U8 { short8 s; uint32_t u[4]; };
    U8 zb0, zb1;
    zb0.u[0] = pk_bf16(a0.x * scz, a0.y * scz);
    zb0.u[1] = pk_bf16(a0.z * scz, a0.w * scz);
    zb0.u[2] = pk_bf16(a1.x * scz, a1.y * scz);
    zb0.u[3] = pk_bf16(a1.z * scz, a1.w * scz);
    zb1.u[0] = pk_bf16(a2.x * scz, a2.y * scz);
    zb1.u[1] = pk_bf16(a2.z * scz, a2.w * scz);
    zb1.u[2] = pk_bf16(a3.x * scz, a3.y * scz);
    zb1.u[3] = pk_bf16(a3.z * scz, a3.w * scz);

    const float B1 = kq * kLog2e;  // static bound: x <= B1

    // ---- all 4 u tiles prefetched upfront (complete under pass 1)
    const float* ur = gum + (size_t)row * 512 + 256 * W;
    float4 uN[4][4];
#pragma unroll
    for (int t = 0; t < 4; ++t)
#pragma unroll
        for (int j = 0; j < 4; ++j)
            uN[t][j] = *(const float4*)(ur + 64 * t + 16 * j + 4 * g);

    __syncthreads();  // LDS codebook ready

    // ================= pass 1: logits -> e (bf16-packed), S, W ============
    uint32_t epk[32];
    float S4[4] = {0.f, 0.f, 0.f, 0.f}, W4[4] = {0.f, 0.f, 0.f, 0.f};
#pragma unroll
    for (int T = 0; T < 4; ++T) {
#pragma unroll
        for (int q = 0; q < 4; ++q) {
            const int R = 256 * W + 64 * T + 16 * q + rh;
            const char* rb = smem + R * 128;
            const short8 ca0 = *(const short8*)(rb + ((g ^ (R & 7)) << 4));
            const short8 ca1 = *(const short8*)(rb + (((g + 4) ^ (R & 7)) << 4));
            f32x4 acc = {0.f, 0.f, 0.f, 0.f};
            acc = __builtin_amdgcn_mfma_f32_16x16x32_bf16(ca0, zb0.s, acc, 0, 0, 0);
            acc = __builtin_amdgcn_mfma_f32_16x16x32_bf16(ca1, zb1.s, acc, 0, 0, 0);
            float e4[4];
#pragma unroll
            for (int i = 0; i < 4; ++i) {
                const float d = acc[i] - B1;
                const float e = __builtin_amdgcn_exp2f(d);
                e4[i] = e;
                S4[i] += e;
                W4[i] = fmaf(d, e, W4[i]);
            }
            epk[8 * T + 2 * q] = pk_bf16(e4[0], e4[1]);
            epk[8 * T + 2 * q + 1] = pk_bf16(e4[2], e4[3]);
        }
    }
    float Sr = (S4[0] + S4[1]) + (S4[2] + S4[3]);
    float Wr = (W4[0] + W4[1]) + (W4[2] + W4[3]);
    Sr += __shfl_xor(Sr, 16, 64);
    Sr += __shfl_xor(Sr, 32, 64);
    Wr += __shfl_xor(Wr, 16, 64);
    Wr += __shfl_xor(Wr, 32, 64);
    if (g == 0) { cS[tp][W][rh] = Sr; cW[tp][W][rh] = Wr; }
    __syncthreads();
    const float St = cS[tp][0][rh] + cS[tp][1][rh];
    const float Wt = cW[tp][0][rh] + cW[tp][1][rh];
    const float inv = 1.0f / St;
    const float kldd = kLn2 * (Wt * inv - __builtin_amdgcn_logf(St));

    // ================= pass 2: avg, gumbel via rcp, GEMM2 =================
    float S24[4] = {0.f, 0.f, 0.f, 0.f};
    f32x4 acc2[4];
#pragma unroll
    for (int dt = 0; dt < 4; ++dt) acc2[dt] = (f32x4){0.f, 0.f, 0.f, 0.f};
    const int srcA = rh + 16 * ((2 * g) & 3);
    const int srcB = rh + 16 * ((2 * g + 1) & 3);
    const bool hi = (g & 2) != 0;

#pragma unroll
    for (int T = 0; T < 4; ++T) {
        // unpack e (bf16 -> f32)
        float ev[16];
#pragma unroll
        for (int k2 = 0; k2 < 8; ++k2) {
            const uint32_t pe = epk[8 * T + k2];
            ev[2 * k2] = __uint_as_float(pe << 16);
            ev[2 * k2 + 1] = __uint_as_float(pe & 0xffff0000u);
        }

        // gumbel: e2 = (e * rcp(-ln(u+eps)+eps))^2 (scales cancel in norm)
        float pf[8];
#pragma unroll
        for (int q = 0; q < 4; ++q) {
            const float uu[4] = {uN[T][q].x, uN[T][q].y, uN[T][q].z, uN[T][q].w};
            float e2v[4];
#pragma unroll
            for (int i = 0; i < 4; ++i) {
                const float lg = __builtin_amdgcn_logf(uu[i] + kEpsG);
                const float inr = fmaf(lg, -kLn2, kEpsG);
                const float r = __builtin_amdgcn_rcpf(inr);
                const float t = ev[4 * q + i] * r;
                const float e2 = t * t;
                e2v[i] = e2;
                S24[i] += e2;
            }
            pf[2 * q] = __uint_as_float(pk_bf16(e2v[0], e2v[1]));
            pf[2 * q + 1] = __uint_as_float(pk_bf16(e2v[2], e2v[3]));
        }

        // p = e*inv; butterfly transpose-reduce over 16 rows (destroys ev)
#pragma unroll
        for (int j = 0; j < 16; ++j) ev[j] *= inv;
#pragma unroll
        for (int m = 1, nv = 8; m <= 8; m <<= 1, nv >>= 1) {
            const bool up_ = (rh & m) != 0;
#pragma unroll
            for (int t = 0; t < nv; ++t) {
                const float a = ev[t], b = ev[t + nv];
                const float keep = up_ ? b : a;
                const float send = up_ ? a : b;
                ev[t] = keep + __shfl_xor(send, m, 64);
            }
        }
        const int jr = ((rh & 1) << 3) | ((rh & 2) << 1) | ((rh & 4) >> 1) |
                       ((rh & 8) >> 3);
        avg4[tp * 512 + 256 * W + 64 * T + 16 * (jr >> 2) + 4 * g + (jr & 3)] =
            ev[0];

        // D->A exchange + GEMM2 (B operand from swizzled LDS)
#pragma unroll
        for (int ks = 0; ks < 2; ++ks) {
            const float a0lo = __shfl(pf[4 * ks + 0], srcA, 64);
            const float a1lo = __shfl(pf[4 * ks + 1], srcA, 64);
            const float a0hi = __shfl(pf[4 * ks + 2], srcA, 64);
            const float a1hi = __shfl(pf[4 * ks + 3], srcA, 64);
            const float b0lo = __shfl(pf[4 * ks + 0], srcB, 64);
            const float b1lo = __shfl(pf[4 * ks + 1], srcB, 64);
            const float b0hi = __shfl(pf[4 * ks + 2], srcB, 64);
            const float b1hi = __shfl(pf[4 * ks + 3], srcB, 64);
            U8 af;
            af.u[0] = __float_as_uint(hi ? a0hi : a0lo);
            af.u[1] = __float_as_uint(hi ? a1hi : a1lo);
            af.u[2] = __float_as_uint(hi ? b0hi : b0lo);
            af.u[3] = __float_as_uint(hi ? b1hi : b1lo);
#pragma unroll
            for (int dt = 0; dt < 4; ++dt) {
                const int D = rh + 16 * dt;
                const int c = 32 * W + 8 * T + 4 * ks + g;
                const short8 bf = *(const short8*)(smem + kOffCbt + D * 1024 +
                                                   ((c ^ (D & 7)) << 4));
                acc2[dt] = __builtin_amdgcn_mfma_f32_16x16x32_bf16(
                    af.s, bf, acc2[dt], 0, 0, 0);
            }
        }
    }

    // ---- merge S2 + exchange acc2 partials (single barrier)
    float S2r = (S24[0] + S24[1]) + (S24[2] + S24[3]);
    S2r += __shfl_xor(S2r, 16, 64);
    S2r += __shfl_xor(S2r, 32, 64);
    if (g == 0) cS2[tp][W][rh] = S2r;
    if (W == 0) {
        accx[tp][0][0][l] = make_float4(acc2[2][0], acc2[2][1], acc2[2][2], acc2[2][3]);
        accx[tp][0][1][l] = make_float4(acc2[3][0], acc2[3][1], acc2[3][2], acc2[3][3]);
    } else {
        accx[tp][1][0][l] = make_float4(acc2[0][0], acc2[0][1], acc2[0][2], acc2[0][3]);
        accx[tp][1][1][l] = make_float4(acc2[1][0], acc2[1][1], acc2[1][2], acc2[1][3]);
    }
    __syncthreads();
    const float inv2 = 1.0f / (cS2[tp][0][rh] + cS2[tp][1][rh]);
    float ivi[4];
#pragma unroll
    for (int i = 0; i < 4; ++i) ivi[i] = __shfl(inv2, 4 * g + i, 64);

    float kldc = 0.f;
#define EPI(OV, XV, DT)                                                       \
    {                                                                         \
        const float oq[4] = {OV[0] + XV.x, OV[1] + XV.y, OV[2] + XV.z,        \
                             OV[3] + XV.w};                                   \
        _Pragma("unroll") for (int i = 0; i < 4; ++i) {                       \
            const float q = oq[i] * ivi[i];                                   \
            const size_t oi = (size_t)(r0 + 4 * g + i) * 64 + rh + 16 * (DT); \
            out[oi] = q;                                                      \
            const float zv = z[oi];                                           \
            kldc = fmaf(zv, zv - q, kldc);                                    \
        }                                                                     \
    }
    if (W == 0) {
        const float4 x0 = accx[tp][1][0][l];
        const float4 x1 = accx[tp][1][1][l];
        EPI(acc2[0], x0, 0)
        EPI(acc2[1], x1, 1)
    } else {
        const float4 x0 = accx[tp][0][0][l];
        const float4 x1 = accx[tp][0][1][l];
        EPI(acc2[2], x0, 2)
        EPI(acc2[3], x1, 3)
    }

    // ---- scalar + avg reductions (wave reductions before divergence)
    const int slot = blockIdx.x & (kSlots - 1);
    float* gp = g_part + (size_t)slot * kStride;
    const float kc = wsum64(kldc) * kq;
    const float kd = wsum64(kldd) * 0.25f;
    if (l == 0) {
        atomicAdd(&gp[513], kc);
        if (W == 0) atomicAdd(&gp[512], kd);
    }
    // avg4 fully written before the accx barrier; 512 threads flush 512 codes
    const float av = avg4[tid] + avg4[512 + tid] + avg4[1024 + tid] +
                     avg4[1536 + tid];
    atomicAdd(&gp[tid], av);
}

__global__ __launch_bounds__(512) void k_final(const float* __restrict__ g_part,
                                               float* __restrict__ out) {
    __shared__ float red[8];
    const int tid = threadIdx.x;
    float sacc = 0.f;
#pragma unroll 8
    for (int i = 0; i < kSlots; ++i) sacc += g_part[(size_t)i * kStride + tid];
    const float avg = sacc * (1.0f / 65536.0f);
    const float t = avg * __logf(avg + kEpsP);
    const float sw = wsum64(t);
    if ((tid & 63) == 0) red[tid >> 6] = sw;
    __syncthreads();
    if (tid == 0) {
        float tot = 0.f;
#pragma unroll
        for (int i = 0; i < 8; ++i) tot += red[i];
        float sc0 = 0.f, sc1 = 0.f;
        for (int i = 0; i < kSlots; ++i) {
            sc0 += g_part[(size_t)i * kStride + 512];
            sc1 += g_part[(size_t)i * kStride + 513];
        }
        out[4194304] = (sc0 + sc1) * 0.125f;
        out[4194305] = __expf(-tot);
    }
}

extern "C" void kernel_launch(void* const* d_in, const int* in_sizes, int n_in,
                              void* d_out, int out_size, void* d_ws, size_t ws_size,
                              hipStream_t stream) {
    (void)in_sizes; (void)n_in; (void)out_size; (void)ws_size;
    const float* z   = (const float*)d_in[0];
    const float* kq  = (const float*)d_in[1];
    const float* cb  = (const float*)d_in[2];
    const float* gum = (const float*)d_in[3];
    float* out = (float*)d_out;

    uint16_t* cbN  = (uint16_t*)d_ws;
    uint16_t* cbNT = cbN + 32768;
    float* g_part  = (float*)(cbNT + 32768);

    (void)hipFuncSetAttribute((const void*)k_main,
                              hipFuncAttributeMaxDynamicSharedMemorySize,
                              kLdsBytes);
    (void)hipMemsetAsync(g_part, 0, kSlots * kStride * sizeof(float), stream);
    k_prep<<<128, 256, 0, stream>>>(cb, cbN, cbNT);
    k_main<<<1024, 512, kLdsBytes, stream>>>(z, kq, gum, cbN, cbNT, out, g_part);
    k_final<<<1, 512, 0, stream>>>(g_part, out);
}

// Round 18
// 84.763 us; speedup vs baseline: 2.0832x; 1.0220x over previous
//
#include <hip/hip_runtime.h>
#include <cstdint>
#include <cstddef>

// VmfVectorQuantizer round 18: R17 (LDS-staged codebook) with pass-1/pass-2
// FUSED: per tile, GEMM1 -> e -> gumbel(e2,pf) -> GEMM2 all in one loop
// (gumbel/GEMM2 never needed the softmax merge; only avg does). One barrier
// mid-kernel; avg butterfly in a short loop B after the S-merge.

typedef __attribute__((ext_vector_type(8))) short short8;
typedef __attribute__((ext_vector_type(4))) float f32x4;

namespace {
constexpr float kEpsG = 1e-10f;
constexpr float kEpsN = 1e-12f;
constexpr float kEpsP = 1e-7f;
constexpr float kLog2e = 1.4426950408889634f;
constexpr float kLn2 = 0.6931471805599453f;
constexpr int kSlots = 128;
constexpr int kStride = 520;
// dynamic LDS layout (bytes)
constexpr int kOffCbt = 65536;    // [64][512] bf16 swizzled      65536
constexpr int kOffAvg = 131072;   // float [4][512]                8192
constexpr int kOffCS  = 139264;   // float [4][2][16] x3           1536
constexpr int kOffAcx = 140800;   // float4 [4][2][2][64]         16384
constexpr int kLdsBytes = 157184;
}

__device__ __forceinline__ float wsum64(float v) {
#pragma unroll
    for (int m = 1; m < 64; m <<= 1) v += __shfl_xor(v, m, 64);
    return v;
}
__device__ __forceinline__ uint32_t pk_bf16(float a, float b) {
    uint32_t ua = __float_as_uint(a), ub = __float_as_uint(b);
    ua += 0x7fffu + ((ua >> 16) & 1u);
    ub += 0x7fffu + ((ub >> 16) & 1u);
    return (ua >> 16) | (ub & 0xffff0000u);
}
__device__ __forceinline__ uint16_t bf16_rne(float a) {
    uint32_t ua = __float_as_uint(a);
    ua += 0x7fffu + ((ua >> 16) & 1u);
    return (uint16_t)(ua >> 16);
}
__device__ __forceinline__ float dot4(float4 v) {
    return v.x * v.x + v.y * v.y + v.z * v.z + v.w * v.w;
}

__global__ __launch_bounds__(256) void k_prep(const float* __restrict__ cb,
                                              uint16_t* __restrict__ cbN,
                                              uint16_t* __restrict__ cbNT) {
    const int row = blockIdx.x * 4 + (threadIdx.x >> 6);
    const int lane = threadIdx.x & 63;
    const float v = cb[row * 64 + lane];
    const float ss = wsum64(v * v);
    const float nv = v / fmaxf(sqrtf(ss), kEpsN);
    const uint16_t h = bf16_rne(nv);
    cbN[row * 64 + lane] = h;
    cbNT[lane * 512 + row] = h;
}

// ---- k_main: 1024 blocks x 512 threads (8 waves = 4 tile-pairs).
__global__ __launch_bounds__(512, 2) void k_main(
    const float* __restrict__ z, const float* __restrict__ kqp,
    const float* __restrict__ gum, const uint16_t* __restrict__ cbN,
    const uint16_t* __restrict__ cbNT, float* __restrict__ out,
    float* __restrict__ g_part) {
    extern __shared__ float4 smem_al[];
    char* smem = (char*)smem_al;
    float* avg4 = (float*)(smem + kOffAvg);
    float (*cS)[2][16]  = (float(*)[2][16])(smem + kOffCS);
    float (*cW)[2][16]  = (float(*)[2][16])(smem + kOffCS + 512);
    float (*cS2)[2][16] = (float(*)[2][16])(smem + kOffCS + 1024);
    float4 (*accx)[2][2][64] = (float4(*)[2][2][64])(smem + kOffAcx);

    const int tid = threadIdx.x;
    const int wv = tid >> 6;   // 0..7
    const int tp = wv >> 1;    // tile-pair 0..3
    const int W = wv & 1;      // code-half
    const int l = tid & 63;
    const int g = l >> 4;
    const int rh = l & 15;
    const int r0 = blockIdx.x * 64 + tp * 16;
    const int row = r0 + rh;
    const float kq = *kqp;

    // ---- stage codebook into swizzled LDS (coalesced 16B chunks) ----
#pragma unroll
    for (int it = 0; it < 16; ++it) {
        const int i = tid + 512 * it;          // chunk id, 8192 total
        const uint4 v = ((const uint4*)cbN)[i];
        const int r = i >> 3, c = i & 7;
        *(uint4*)(smem + r * 128 + (((c ^ (r & 7))) << 4)) = v;
    }
#pragma unroll
    for (int it = 0; it < 8; ++it) {
        const int i = tid + 512 * it;          // chunk id, 4096 total
        const uint4 v = ((const uint4*)cbNT)[i];
        const int d = i >> 6, c = i & 63;
        *(uint4*)(smem + kOffCbt + d * 1024 + ((c ^ (d & 7)) << 4)) = v;
    }

    // ---- z load + L2 normalize; fold kq*log2e into bf16 B-fragments
    const float* zr = z + (size_t)row * 64;
    const float4 a0 = *(const float4*)(zr + 8 * g);
    const float4 a1 = *(const float4*)(zr + 8 * g + 4);
    const float4 a2 = *(const float4*)(zr + 32 + 8 * g);
    const float4 a3 = *(const float4*)(zr + 36 + 8 * g);
    float ss = dot4(a0) + dot4(a1) + dot4(a2) + dot4(a3);
    ss += __shfl_xor(ss, 16, 64);
    ss += __shfl_xor(ss, 32, 64);
    const float scz = kq * kLog2e / fmaxf(sqrtf(ss), kEpsN);
    union U8 { short8 s; uint32_t u[4]; };
    U8 zb0, zb1;
    zb0.u[0] = pk_bf16(a0.x * scz, a0.y * scz);
    zb0.u[1] = pk_bf16(a0.z * scz, a0.w * scz);
    zb0.u[2] = pk_bf16(a1.x * scz, a1.y * scz);
    zb0.u[3] = pk_bf16(a1.z * scz, a1.w * scz);
    zb1.u[0] = pk_bf16(a2.x * scz, a2.y * scz);
    zb1.u[1] = pk_bf16(a2.z * scz, a2.w * scz);
    zb1.u[2] = pk_bf16(a3.x * scz, a3.y * scz);
    zb1.u[3] = pk_bf16(a3.z * scz, a3.w * scz);

    const float B1 = kq * kLog2e;  // static bound: x <= B1

    // ---- u tiles 0,1 prefetched (ping-pong buffers)
    const float* ur = gum + (size_t)row * 512 + 256 * W;
    float4 uA[4], uB[4];
#pragma unroll
    for (int j = 0; j < 4; ++j) uA[j] = *(const float4*)(ur + 16 * j + 4 * g);
#pragma unroll
    for (int j = 0; j < 4; ++j)
        uB[j] = *(const float4*)(ur + 64 + 16 * j + 4 * g);

    __syncthreads();  // LDS codebook ready

    // ============== fused loop: GEMM1 -> e -> gumbel -> GEMM2 =============
    uint32_t epk[32];
    float S4[4] = {0.f, 0.f, 0.f, 0.f}, W4[4] = {0.f, 0.f, 0.f, 0.f};
    float S24[4] = {0.f, 0.f, 0.f, 0.f};
    f32x4 acc2[4];
#pragma unroll
    for (int dt = 0; dt < 4; ++dt) acc2[dt] = (f32x4){0.f, 0.f, 0.f, 0.f};
    const int srcA = rh + 16 * ((2 * g) & 3);
    const int srcB = rh + 16 * ((2 * g + 1) & 3);
    const bool hi = (g & 2) != 0;

#define RELOAD(UB, RT)                                                       \
    _Pragma("unroll") for (int j = 0; j < 4; ++j)                            \
        UB[j] = *(const float4*)(ur + 64 * (RT) + 16 * j + 4 * g);

#define FTILE(T, UBUF, PRE)                                                  \
    {                                                                        \
        float pf[8];                                                         \
        _Pragma("unroll") for (int q = 0; q < 4; ++q) {                      \
            const int R = 256 * W + 64 * (T) + 16 * q + rh;                  \
            const char* rb = smem + R * 128;                                 \
            const short8 ca0 = *(const short8*)(rb + ((g ^ (R & 7)) << 4));  \
            const short8 ca1 =                                               \
                *(const short8*)(rb + (((g + 4) ^ (R & 7)) << 4));           \
            f32x4 acc = {0.f, 0.f, 0.f, 0.f};                                \
            acc = __builtin_amdgcn_mfma_f32_16x16x32_bf16(ca0, zb0.s, acc,   \
                                                          0, 0, 0);          \
            acc = __builtin_amdgcn_mfma_f32_16x16x32_bf16(ca1, zb1.s, acc,   \
                                                          0, 0, 0);          \
            const float uu[4] = {UBUF[q].x, UBUF[q].y, UBUF[q].z, UBUF[q].w};\
            float e4[4], e2v[4];                                             \
            _Pragma("unroll") for (int i = 0; i < 4; ++i) {                  \
                const float d = acc[i] - B1;                                 \
                const float e = __builtin_amdgcn_exp2f(d);                   \
                e4[i] = e;                                                   \
                S4[i] += e;                                                  \
                W4[i] = fmaf(d, e, W4[i]);                                   \
                const float lg = __builtin_amdgcn_logf(uu[i] + kEpsG);       \
                const float inr = fmaf(lg, -kLn2, kEpsG);                    \
                const float r = __builtin_amdgcn_rcpf(inr);                  \
                const float t = e * r;                                       \
                const float e2 = t * t;                                      \
                e2v[i] = e2;                                                 \
                S24[i] += e2;                                                \
            }                                                                \
            epk[8 * (T) + 2 * q] = pk_bf16(e4[0], e4[1]);                    \
            epk[8 * (T) + 2 * q + 1] = pk_bf16(e4[2], e4[3]);                \
            pf[2 * q] = __uint_as_float(pk_bf16(e2v[0], e2v[1]));            \
            pf[2 * q + 1] = __uint_as_float(pk_bf16(e2v[2], e2v[3]));        \
        }                                                                    \
        PRE                                                                  \
        _Pragma("unroll") for (int ks = 0; ks < 2; ++ks) {                   \
            const float a0lo = __shfl(pf[4 * ks + 0], srcA, 64);             \
            const float a1lo = __shfl(pf[4 * ks + 1], srcA, 64);             \
            const float a0hi = __shfl(pf[4 * ks + 2], srcA, 64);             \
            const float a1hi = __shfl(pf[4 * ks + 3], srcA, 64);             \
            const float b0lo = __shfl(pf[4 * ks + 0], srcB, 64);             \
            const float b1lo = __shfl(pf[4 * ks + 1], srcB, 64);             \
            const float b0hi = __shfl(pf[4 * ks + 2], srcB, 64);             \
            const float b1hi = __shfl(pf[4 * ks + 3], srcB, 64);             \
            U8 af;                                                           \
            af.u[0] = __float_as_uint(hi ? a0hi : a0lo);                     \
            af.u[1] = __float_as_uint(hi ? a1hi : a1lo);                     \
            af.u[2] = __float_as_uint(hi ? b0hi : b0lo);                     \
            af.u[3] = __float_as_uint(hi ? b1hi : b1lo);                     \
            _Pragma("unroll") for (int dt = 0; dt < 4; ++dt) {               \
                const int D = rh + 16 * dt;                                  \
                const int c = 32 * W + 8 * (T) + 4 * ks + g;                 \
                const short8 bf = *(const short8*)(smem + kOffCbt +          \
                    D * 1024 + ((c ^ (D & 7)) << 4));                        \
                acc2[dt] = __builtin_amdgcn_mfma_f32_16x16x32_bf16(          \
                    af.s, bf, acc2[dt], 0, 0, 0);                            \
            }                                                                \
        }                                                                    \
    }

    FTILE(0, uA, RELOAD(uA, 2))
    FTILE(1, uB, RELOAD(uB, 3))
    FTILE(2, uA, ;)
    FTILE(3, uB, ;)

    // ---- merge softmax-1 stats (single barrier)
    float Sr = (S4[0] + S4[1]) + (S4[2] + S4[3]);
    float Wr = (W4[0] + W4[1]) + (W4[2] + W4[3]);
    Sr += __shfl_xor(Sr, 16, 64);
    Sr += __shfl_xor(Sr, 32, 64);
    Wr += __shfl_xor(Wr, 16, 64);
    Wr += __shfl_xor(Wr, 32, 64);
    if (g == 0) { cS[tp][W][rh] = Sr; cW[tp][W][rh] = Wr; }
    __syncthreads();
    const float St = cS[tp][0][rh] + cS[tp][1][rh];
    const float Wt = cW[tp][0][rh] + cW[tp][1][rh];
    const float inv = 1.0f / St;
    const float kldd = kLn2 * (Wt * inv - __builtin_amdgcn_logf(St));

    // ============== loop B: avg_probs butterfly ===========================
#pragma unroll
    for (int T = 0; T < 4; ++T) {
        float ev[16];
#pragma unroll
        for (int k2 = 0; k2 < 8; ++k2) {
            const uint32_t pe = epk[8 * T + k2];
            ev[2 * k2] = __uint_as_float(pe << 16);
            ev[2 * k2 + 1] = __uint_as_float(pe & 0xffff0000u);
        }
#pragma unroll
        for (int j = 0; j < 16; ++j) ev[j] *= inv;
#pragma unroll
        for (int m = 1, nv = 8; m <= 8; m <<= 1, nv >>= 1) {
            const bool up_ = (rh & m) != 0;
#pragma unroll
            for (int t = 0; t < nv; ++t) {
                const float a = ev[t], b = ev[t + nv];
                const float keep = up_ ? b : a;
                const float send = up_ ? a : b;
                ev[t] = keep + __shfl_xor(send, m, 64);
            }
        }
        const int jr = ((rh & 1) << 3) | ((rh & 2) << 1) | ((rh & 4) >> 1) |
                       ((rh & 8) >> 3);
        avg4[tp * 512 + 256 * W + 64 * T + 16 * (jr >> 2) + 4 * g + (jr & 3)] =
            ev[0];
    }

    // ---- merge S2 + exchange acc2 partials (single barrier)
    float S2r = (S24[0] + S24[1]) + (S24[2] + S24[3]);
    S2r += __shfl_xor(S2r, 16, 64);
    S2r += __shfl_xor(S2r, 32, 64);
    if (g == 0) cS2[tp][W][rh] = S2r;
    if (W == 0) {
        accx[tp][0][0][l] = make_float4(acc2[2][0], acc2[2][1], acc2[2][2], acc2[2][3]);
        accx[tp][0][1][l] = make_float4(acc2[3][0], acc2[3][1], acc2[3][2], acc2[3][3]);
    } else {
        accx[tp][1][0][l] = make_float4(acc2[0][0], acc2[0][1], acc2[0][2], acc2[0][3]);
        accx[tp][1][1][l] = make_float4(acc2[1][0], acc2[1][1], acc2[1][2], acc2[1][3]);
    }
    __syncthreads();
    const float inv2 = 1.0f / (cS2[tp][0][rh] + cS2[tp][1][rh]);
    float ivi[4];
#pragma unroll
    for (int i = 0; i < 4; ++i) ivi[i] = __shfl(inv2, 4 * g + i, 64);

    float kldc = 0.f;
#define EPI(OV, XV, DT)                                                       \
    {                                                                         \
        const float oq[4] = {OV[0] + XV.x, OV[1] + XV.y, OV[2] + XV.z,        \
                             OV[3] + XV.w};                                   \
        _Pragma("unroll") for (int i = 0; i < 4; ++i) {                       \
            const float q = oq[i] * ivi[i];                                   \
            const size_t oi = (size_t)(r0 + 4 * g + i) * 64 + rh + 16 * (DT); \
            out[oi] = q;                                                      \
            const float zv = z[oi];                                           \
            kldc = fmaf(zv, zv - q, kldc);                                    \
        }                                                                     \
    }
    if (W == 0) {
        const float4 x0 = accx[tp][1][0][l];
        const float4 x1 = accx[tp][1][1][l];
        EPI(acc2[0], x0, 0)
        EPI(acc2[1], x1, 1)
    } else {
        const float4 x0 = accx[tp][0][0][l];
        const float4 x1 = accx[tp][0][1][l];
        EPI(acc2[2], x0, 2)
        EPI(acc2[3], x1, 3)
    }

    // ---- scalar + avg reductions (wave reductions before divergence)
    const int slot = blockIdx.x & (kSlots - 1);
    float* gp = g_part + (size_t)slot * kStride;
    const float kc = wsum64(kldc) * kq;
    const float kd = wsum64(kldd) * 0.25f;
    if (l == 0) {
        atomicAdd(&gp[513], kc);
        if (W == 0) atomicAdd(&gp[512], kd);
    }
    // avg4 fully written before the accx barrier; 512 threads flush 512 codes
    const float av = avg4[tid] + avg4[512 + tid] + avg4[1024 + tid] +
                     avg4[1536 + tid];
    atomicAdd(&gp[tid], av);
}

__global__ __launch_bounds__(512) void k_final(const float* __restrict__ g_part,
                                               float* __restrict__ out) {
    __shared__ float red[8];
    const int tid = threadIdx.x;
    float sacc = 0.f;
#pragma unroll 8
    for (int i = 0; i < kSlots; ++i) sacc += g_part[(size_t)i * kStride + tid];
    const float avg = sacc * (1.0f / 65536.0f);
    const float t = avg * __logf(avg + kEpsP);
    const float sw = wsum64(t);
    if ((tid & 63) == 0) red[tid >> 6] = sw;
    __syncthreads();
    if (tid == 0) {
        float tot = 0.f;
#pragma unroll
        for (int i = 0; i < 8; ++i) tot += red[i];
        float sc0 = 0.f, sc1 = 0.f;
        for (int i = 0; i < kSlots; ++i) {
            sc0 += g_part[(size_t)i * kStride + 512];
            sc1 += g_part[(size_t)i * kStride + 513];
        }
        out[4194304] = (sc0 + sc1) * 0.125f;
        out[4194305] = __expf(-tot);
    }
}

extern "C" void kernel_launch(void* const* d_in, const int* in_sizes, int n_in,
                              void* d_out, int out_size, void* d_ws, size_t ws_size,
                              hipStream_t stream) {
    (void)in_sizes; (void)n_in; (void)out_size; (void)ws_size;
    const float* z   = (const float*)d_in[0];
    const float* kq  = (const float*)d_in[1];
    const float* cb  = (const float*)d_in[2];
    const float* gum = (const float*)d_in[3];
    float* out = (float*)d_out;

    uint16_t* cbN  = (uint16_t*)d_ws;
    uint16_t* cbNT = cbN + 32768;
    float* g_part  = (float*)(cbNT + 32768);

    (void)hipFuncSetAttribute((const void*)k_main,
                              hipFuncAttributeMaxDynamicSharedMemorySize,
                              kLdsBytes);
    (void)hipMemsetAsync(g_part, 0, kSlots * kStride * sizeof(float), stream);
    k_prep<<<128, 256, 0, stream>>>(cb, cbN, cbNT);
    k_main<<<1024, 512, kLdsBytes, stream>>>(z, kq, gum, cbN, cbNT, out, g_part);
    k_final<<<1, 512, 0, stream>>>(g_part, out);
}